// Round 6
// baseline (56.300 us; speedup 1.0000x reference)
//
#include <hip/hip_runtime.h>
#include <hip/hip_bf16.h>

#define IN_F  4096
#define OUT_F 11008

typedef _Float16 half8 __attribute__((ext_vector_type(8)));
typedef _Float16 half4 __attribute__((ext_vector_type(4)));
typedef float    f32x4 __attribute__((ext_vector_type(4)));
typedef int      i32x4 __attribute__((ext_vector_type(4)));

// Single fused kernel. Block: 16 output channels, 256 threads = 4 waves.
// Wave w owns K slice [w*1024, w*1024+1024) = 16 chunks of 64 k.
//  - weights: COALESCED 16 rows x dense 64B lines -> regs -> cvt fp16 ->
//    wave-private LDS tile (160B row stride) -> ds_read_b128 fragments.
//  - x: lane-private divergent f32 fragment loads (L2-resident, 2x f32x4
//    per fragment) -> cvt fp16 in regs. No prepack kernel, no workspace.
//  - 2-deep register prefetch (static indexing), no main-loop __syncthreads.
__global__ __launch_bounds__(256, 4)
void dql_fused(const float* __restrict__ x,      // [32][4096] f32 (exact fp16 vals)
               const int* __restrict__ wq,       // [11008][4096] int32 in [-127,127]
               const float* __restrict__ scale,  // [11008]
               const float* __restrict__ bias,   // [11008]
               float* __restrict__ out)          // [32][11008]
{
    __shared__ __align__(16) _Float16 wlds[4][16][80];  // 160B row stride
    __shared__ float red[4][64][9];

    const int tid  = threadIdx.x;
    const int wid  = tid >> 6;
    const int lane = tid & 63;
    const int c    = lane & 15;           // fragment: B channel row / A token row
    const int kg   = lane >> 4;           // fragment: k-group (8 k each)
    const int srow = lane >> 2;           // weight staging: row (0..15)
    const int scol = (lane & 3) * 4;      // weight staging: int offset
    const int obase = blockIdx.x * 16;
    const int kbase = wid * 1024;

    const int*   wrow = wq + (size_t)(obase + srow) * IN_F + kbase + scol;
    const float* xrow = x + (size_t)c * IN_F + kbase + kg * 8;  // h=0; h=1 at +16*IN_F

    f32x4 acc0 = {0.f, 0.f, 0.f, 0.f};
    f32x4 acc1 = {0.f, 0.f, 0.f, 0.f};

    i32x4 wa[4], wb[4];
    f32x4 xa[8], xb[8];   // [ (sub*2+h)*2 + piece ]

    auto LOADW = [&](i32x4* wbuf, int ch) {
        #pragma unroll
        for (int i = 0; i < 4; ++i)
            wbuf[i] = *(const i32x4*)(wrow + ch * 64 + i * 16);
    };
    auto LOADX = [&](f32x4* xbuf, int ch) {
        #pragma unroll
        for (int sub = 0; sub < 2; ++sub)
            #pragma unroll
            for (int h = 0; h < 2; ++h)
                #pragma unroll
                for (int p = 0; p < 2; ++p)
                    xbuf[(sub * 2 + h) * 2 + p] =
                        *(const f32x4*)(xrow + (size_t)h * 16 * IN_F + ch * 64 + sub * 32 + p * 4);
    };
    auto BODY = [&](i32x4* wcur, f32x4* xcur, i32x4* wnxt, f32x4* xnxt, int ch) {
        if (ch + 1 < 16) { LOADW(wnxt, ch + 1); LOADX(xnxt, ch + 1); }
        // stage current chunk's weights to LDS (cvt int -> fp16, exact)
        #pragma unroll
        for (int i = 0; i < 4; ++i) {
            half4 cv;
            #pragma unroll
            for (int j = 0; j < 4; ++j) cv[j] = (_Float16)wcur[i][j];
            *(half4*)&wlds[wid][srow][scol + i * 16] = cv;
        }
        // compute: 2 k-steps of 32
        #pragma unroll
        for (int sub = 0; sub < 2; ++sub) {
            half8 wf = *(half8*)&wlds[wid][c][sub * 32 + kg * 8];
            #pragma unroll
            for (int h = 0; h < 2; ++h) {
                half8 xf;
                #pragma unroll
                for (int j = 0; j < 4; ++j) {
                    xf[j]     = (_Float16)xcur[(sub * 2 + h) * 2 + 0][j];  // exact: x was fp16
                    xf[4 + j] = (_Float16)xcur[(sub * 2 + h) * 2 + 1][j];
                }
                if (h == 0) acc0 = __builtin_amdgcn_mfma_f32_16x16x32_f16(xf, wf, acc0, 0, 0, 0);
                else        acc1 = __builtin_amdgcn_mfma_f32_16x16x32_f16(xf, wf, acc1, 0, 0, 0);
            }
        }
    };

    LOADW(wa, 0); LOADX(xa, 0);
    #pragma unroll
    for (int ch = 0; ch < 16; ch += 2) {
        BODY(wa, xa, wb, xb, ch);
        BODY(wb, xb, wa, xa, ch + 1);
    }

    #pragma unroll
    for (int r = 0; r < 4; ++r) {
        red[wid][lane][r]     = acc0[r];
        red[wid][lane][4 + r] = acc1[r];
    }
    __syncthreads();

    #pragma unroll
    for (int sp = 0; sp < 2; ++sp) {
        const int slot = (tid >> 6) * 2 + sp;    // 0..7
        const int rl   = tid & 63;
        float s = 0.f;
        #pragma unroll
        for (int w = 0; w < 4; ++w) s += red[w][rl][slot];
        const int h = slot >> 2;
        const int r = slot & 3;
        const int t = h * 16 + (rl >> 4) * 4 + r;   // token
        const int o = obase + (rl & 15);            // channel
        out[t * OUT_F + o] = s * scale[o] + bias[o];
    }
}

extern "C" void kernel_launch(void* const* d_in, const int* in_sizes, int n_in,
                              void* d_out, int out_size, void* d_ws, size_t ws_size,
                              hipStream_t stream) {
    const float* x     = (const float*)d_in[0];
    const int*   wq    = (const int*)d_in[1];
    const float* scale = (const float*)d_in[2];
    const float* bias  = (const float*)d_in[3];
    float*       out   = (float*)d_out;

    dql_fused<<<OUT_F / 16, 256, 0, stream>>>(x, wq, scale, bias, out);
}

// Round 8
// 37.063 us; speedup vs baseline: 1.5190x; 1.5190x over previous
//
#include <hip/hip_runtime.h>
#include <hip/hip_bf16.h>

#define IN_F  4096
#define OUT_F 11008

typedef _Float16 half8 __attribute__((ext_vector_type(8)));
typedef _Float16 half4 __attribute__((ext_vector_type(4)));
typedef __fp16   fp16x2 __attribute__((ext_vector_type(2)));
typedef float    f32x4 __attribute__((ext_vector_type(4)));
typedef int      i32x4 __attribute__((ext_vector_type(4)));

// d_ws layout (256 KB): prepacked x A-fragments (fp16).
// For k-step s (0..127), token-half h (0..1), lane l (0..63):
//   8 halfs at xws + ((s*2 + h)*64 + l)*8
//   element j = x[h*16 + (l&15)][s*32 + (l>>4)*8 + j]
__global__ __launch_bounds__(256, 4)
void prepack_x(const float* __restrict__ x, _Float16* __restrict__ xws) {
    const int idx = blockIdx.x * 256 + threadIdx.x;   // 0..16383
    const int l = idx & 63;
    const int h = (idx >> 6) & 1;
    const int s = idx >> 7;
    const float* src = x + (size_t)(h * 16 + (l & 15)) * IN_F + s * 32 + (l >> 4) * 8;
    half8 v;
    #pragma unroll
    for (int j = 0; j < 8; ++j) v[j] = (_Float16)src[j];
    *(half8*)(xws + (size_t)idx * 8) = v;
}

// Main: block = 16 output channels, 512 threads = 8 waves.
// Wave w owns K slice [w*512, w*512+512) = 8 chunks of 64 k.
//  - weights: COALESCED (16 rows x dense 64B lines) -> regs -> cvt_pkrtz fp16
//    -> wave-private LDS tile (144B row stride, 2-way-free banks) ->
//    ds_read_b128 fragments.
//  - x: prepacked fragments, 1 coalesced dwordx4 per MFMA operand.
//  - 2-deep register prefetch, no main-loop __syncthreads.
__global__ __launch_bounds__(512, 4)
void dql_main(const int* __restrict__ wq,           // [11008][4096] int32
              const _Float16* __restrict__ xws,     // prepacked fragments
              const float* __restrict__ scale,      // [11008]
              const float* __restrict__ bias,       // [11008]
              float* __restrict__ out)              // [32][11008]
{
    __shared__ __align__(16) _Float16 wlds[8][16][72];  // 144B row stride
    __shared__ float red[8][64][9];

    const int tid  = threadIdx.x;
    const int wid  = tid >> 6;
    const int lane = tid & 63;
    const int c    = lane & 15;           // fragment: channel row / token row
    const int kg   = lane >> 4;           // fragment: k-group (8 k each)
    const int srow = lane >> 2;           // weight staging: row (0..15)
    const int scol = (lane & 3) * 4;      // weight staging: int offset in chunk
    const int obase = blockIdx.x * 16;
    const int kbase = wid * 512;

    const int* wrow = wq + (size_t)(obase + srow) * IN_F + kbase + scol;
    // half8 index base: (s*2+h)*64 + lane, s = wid*16 + ch*2 + sub
    const _Float16* xbase = xws + ((size_t)(wid * 32) * 64 + lane) * 8;

    f32x4 acc0 = {0.f, 0.f, 0.f, 0.f};
    f32x4 acc1 = {0.f, 0.f, 0.f, 0.f};

    i32x4 wa[4], wb[4], xa[4], xb[4];

    auto LOADW = [&](i32x4* wbuf, int ch) {
        #pragma unroll
        for (int i = 0; i < 4; ++i)
            wbuf[i] = *(const i32x4*)(wrow + ch * 64 + i * 16);
    };
    auto LOADX = [&](i32x4* xbuf, int ch) {
        #pragma unroll
        for (int q = 0; q < 4; ++q)       // q = sub*2 + h
            xbuf[q] = *(const i32x4*)(xbase + (size_t)(ch * 4 + q) * 512);
    };
    auto BODY = [&](i32x4* wcur, i32x4* xcur, i32x4* wnxt, i32x4* xnxt, int ch) {
        if (ch + 1 < 8) { LOADW(wnxt, ch + 1); LOADX(xnxt, ch + 1); }
        // stage current chunk's weights to LDS: int -> f32 (exact) ->
        // packed f16 via cvt_pkrtz (exact for |w|<=127), b64 writes
        #pragma unroll
        for (int i = 0; i < 4; ++i) {
            union { fp16x2 v2[2]; half4 v4; } u;
            u.v2[0] = __builtin_amdgcn_cvt_pkrtz((float)wcur[i][0], (float)wcur[i][1]);
            u.v2[1] = __builtin_amdgcn_cvt_pkrtz((float)wcur[i][2], (float)wcur[i][3]);
            *(half4*)&wlds[wid][srow][scol + i * 16] = u.v4;
        }
        // compute: 2 k-steps of 32
        #pragma unroll
        for (int sub = 0; sub < 2; ++sub) {
            half8 wf  = *(half8*)&wlds[wid][c][sub * 32 + kg * 8];
            half8 xf0 = *(half8*)&xcur[sub * 2 + 0];
            half8 xf1 = *(half8*)&xcur[sub * 2 + 1];
            acc0 = __builtin_amdgcn_mfma_f32_16x16x32_f16(xf0, wf, acc0, 0, 0, 0);
            acc1 = __builtin_amdgcn_mfma_f32_16x16x32_f16(xf1, wf, acc1, 0, 0, 0);
        }
    };

    LOADW(wa, 0); LOADX(xa, 0);
    #pragma unroll
    for (int ch = 0; ch < 8; ch += 2) {
        BODY(wa, xa, wb, xb, ch);
        BODY(wb, xb, wa, xa, ch + 1);
    }

    #pragma unroll
    for (int r = 0; r < 4; ++r) {
        red[wid][lane][r]     = acc0[r];
        red[wid][lane][4 + r] = acc1[r];
    }
    __syncthreads();

    // 512 threads: one (lane, slot) each; sum the 8 wave partials.
    const int rlane = tid & 63;
    const int slot  = tid >> 6;          // 0..7 : (token-half h = slot>>2, reg r = slot&3)
    float s = 0.f;
    #pragma unroll
    for (int w = 0; w < 8; ++w) s += red[w][rlane][slot];

    const int h = slot >> 2;
    const int r = slot & 3;
    const int t = h * 16 + (rlane >> 4) * 4 + r;   // token
    const int o = obase + (rlane & 15);            // output channel

    out[t * OUT_F + o] = s * scale[o] + bias[o];
}

// Fallback if workspace is unavailable: R2 kernel (passed at 70.5 us).
__global__ __launch_bounds__(512, 4)
void dql_fallback(const float* __restrict__ x,
                  const int* __restrict__ wq,
                  const float* __restrict__ scale,
                  const float* __restrict__ bias,
                  float* __restrict__ out)
{
    __shared__ float red[8][64][9];

    const int tid  = threadIdx.x;
    const int wid  = tid >> 6;
    const int lane = tid & 63;
    const int c    = lane & 15;
    const int kg   = lane >> 4;
    const int obase = blockIdx.x * 16;
    const int kwave = wid * 512;

    f32x4 acc0 = {0.f, 0.f, 0.f, 0.f};
    f32x4 acc1 = {0.f, 0.f, 0.f, 0.f};

    const int*   wp  = wq + (size_t)(obase + c) * IN_F + kwave + kg * 8;
    const float* xp0 = x + c * IN_F + kwave + kg * 8;
    const float* xp1 = xp0 + 16 * IN_F;

    #pragma unroll 4
    for (int it = 0; it < 16; ++it) {
        i32x4 b0 = *(const i32x4*)(wp);
        i32x4 b1 = *(const i32x4*)(wp + 4);
        f32x4 a0l = *(const f32x4*)(xp0);
        f32x4 a0h = *(const f32x4*)(xp0 + 4);
        f32x4 a1l = *(const f32x4*)(xp1);
        f32x4 a1h = *(const f32x4*)(xp1 + 4);

        half8 afrag0, afrag1, bfrag;
        #pragma unroll
        for (int j = 0; j < 4; ++j) {
            bfrag[j]      = (_Float16)b0[j];
            bfrag[4 + j]  = (_Float16)b1[j];
            afrag0[j]     = (_Float16)a0l[j];
            afrag0[4 + j] = (_Float16)a0h[j];
            afrag1[j]     = (_Float16)a1l[j];
            afrag1[4 + j] = (_Float16)a1h[j];
        }

        acc0 = __builtin_amdgcn_mfma_f32_16x16x32_f16(afrag0, bfrag, acc0, 0, 0, 0);
        acc1 = __builtin_amdgcn_mfma_f32_16x16x32_f16(afrag1, bfrag, acc1, 0, 0, 0);

        wp  += 32;
        xp0 += 32;
        xp1 += 32;
    }

    #pragma unroll
    for (int r = 0; r < 4; ++r) {
        red[wid][lane][r]     = acc0[r];
        red[wid][lane][4 + r] = acc1[r];
    }
    __syncthreads();

    const int rlane = tid & 63;
    const int slot  = tid >> 6;
    float s = 0.f;
    #pragma unroll
    for (int w = 0; w < 8; ++w) s += red[w][rlane][slot];

    const int h = slot >> 2;
    const int r = slot & 3;
    const int t = h * 16 + (rlane >> 4) * 4 + r;
    const int o = obase + (rlane & 15);

    out[t * OUT_F + o] = s * scale[o] + bias[o];
}

extern "C" void kernel_launch(void* const* d_in, const int* in_sizes, int n_in,
                              void* d_out, int out_size, void* d_ws, size_t ws_size,
                              hipStream_t stream) {
    const float* x     = (const float*)d_in[0];
    const int*   wq    = (const int*)d_in[1];
    const float* scale = (const float*)d_in[2];
    const float* bias  = (const float*)d_in[3];
    float*       out   = (float*)d_out;

    if (ws_size >= (size_t)262144 && d_ws != nullptr) {
        _Float16* xws = (_Float16*)d_ws;
        prepack_x<<<64, 256, 0, stream>>>(x, xws);
        dql_main<<<OUT_F / 16, 512, 0, stream>>>(wq, xws, scale, bias, out);
    } else {
        dql_fallback<<<OUT_F / 16, 512, 0, stream>>>(x, wq, scale, bias, out);
    }
}